// Round 1
// baseline (311.195 us; speedup 1.0000x reference)
//
#include <hip/hip_runtime.h>
#include <math.h>

// Problem constants (from reference)
#define B_    16
#define H_    32
#define HKV_  8
#define G_    4      // H / HKV
#define D_    128
#define DV_   128
#define S_    8192
#define M_    64
#define BN_   64
#define SPLIT_ 8
#define BLK_PER_SPLIT (M_ / SPLIT_)     // 8 blocks per split chunk
#define KVSTRIDE (HKV_ * D_)            // 1024 floats between consecutive positions

// ---------------------------------------------------------------------------
// Kernel 1: per (b, hkv, split) partial flash-attention over 8 KV blocks.
// 256 threads = 4 waves; wave w handles head g = w (all 4 GQA heads share KV).
// Lane layout for QK: key j = lane>>2 (16 keys/batch, 4 batches), dim chunk
// c = lane&3 (32 dims). q slice kept in 32 VGPRs, pre-scaled by 1/sqrt(D)*log2e
// so softmax runs in exp2 domain. No LDS, no barriers.
// ---------------------------------------------------------------------------
__global__ __launch_bounds__(256, 4)
void sfa_partial(const float* __restrict__ q,
                 const float* __restrict__ K,
                 const float* __restrict__ V,
                 const int*   __restrict__ blk_idx,
                 const int*   __restrict__ seqlens,
                 float* __restrict__ o_ws,    // [B*HKV*G*SPLIT][DV]
                 float* __restrict__ ml_ws)   // [B*HKV*G*SPLIT][2]
{
    const int wg  = blockIdx.x;            // (b*HKV + hkv)*SPLIT + sp
    const int sp  = wg % SPLIT_;
    const int bh  = wg / SPLIT_;           // b*HKV + hkv
    const int hkv = bh % HKV_;
    const int b   = bh / HKV_;

    const int tid  = threadIdx.x;
    const int wave = tid >> 6;              // == head-in-group g
    const int lane = tid & 63;
    const int c    = lane & 3;              // 32-dim chunk
    const int jr   = lane >> 2;             // key index within 16-key batch

    const int h = hkv * G_ + wave;
    // 1/sqrt(128) * log2(e): scores land directly in exp2 domain
    const float kscale = 0.08838834764831845f * 1.4426950408889634f;

    // Load this lane's 32-dim q slice, pre-scaled (8 float4 = 32 VGPR)
    float4 q4[8];
    {
        const float* qp = q + (size_t)(b * H_ + h) * D_ + c * 32;
        #pragma unroll
        for (int f = 0; f < 8; ++f) {
            float4 t = *(const float4*)(qp + f * 4);
            q4[f] = make_float4(t.x * kscale, t.y * kscale,
                                t.z * kscale, t.w * kscale);
        }
    }

    const int seqlen = seqlens[b];
    const int* bip = blk_idx + (b * HKV_ + hkv) * M_ + sp * BLK_PER_SPLIT;

    const float* Kb = K + (size_t)b * S_ * KVSTRIDE + hkv * D_;
    const float* Vb = V + (size_t)b * S_ * KVSTRIDE + hkv * D_;

    float m  = -INFINITY;   // running max (exp2 domain)
    float l  = 0.f;         // running sum of exp2
    float o0 = 0.f, o1 = 0.f;   // output dims 2*lane, 2*lane+1 (unnormalized)

    for (int bi = 0; bi < BLK_PER_SPLIT; ++bi) {
        const int blk = bip[bi];
        if (blk < 0) continue;              // invalid block: skip (uniform)
        const int pos0 = blk * BN_;

        // ---- QK^T: 64 scores for this wave's head ----
        float s[4];
        #pragma unroll
        for (int bt = 0; bt < 4; ++bt) {
            const int j   = bt * 16 + jr;
            const int pos = pos0 + j;
            const float* kp = Kb + (size_t)pos * KVSTRIDE + c * 32;
            float acc = 0.f;
            #pragma unroll
            for (int f = 0; f < 8; ++f) {
                float4 k4 = *(const float4*)(kp + f * 4);
                acc += q4[f].x * k4.x;
                acc += q4[f].y * k4.y;
                acc += q4[f].z * k4.z;
                acc += q4[f].w * k4.w;
            }
            // sum the 4 dim-chunks (lanes c=0..3 of this key's group)
            acc += __shfl_xor(acc, 1);
            acc += __shfl_xor(acc, 2);
            s[bt] = (pos < seqlen) ? acc : -INFINITY;
        }

        // ---- block max (values already uniform within 4-lane groups) ----
        float bmax = fmaxf(fmaxf(s[0], s[1]), fmaxf(s[2], s[3]));
        #pragma unroll
        for (int off = 4; off < 64; off <<= 1)
            bmax = fmaxf(bmax, __shfl_xor(bmax, off));
        if (bmax == -INFINITY) continue;    // fully masked block

        const float newm = fmaxf(m, bmax);
        const float r = __builtin_amdgcn_exp2f(m - newm);  // m=-inf -> 0

        float p[4];
        float ps = 0.f;
        #pragma unroll
        for (int bt = 0; bt < 4; ++bt) {
            p[bt] = __builtin_amdgcn_exp2f(s[bt] - newm);  // masked -> 0
            ps += p[bt];
        }
        #pragma unroll
        for (int off = 4; off < 64; off <<= 1)
            ps += __shfl_xor(ps, off);

        l  = l * r + ps;
        o0 *= r;
        o1 *= r;
        m  = newm;

        // ---- PV: lane owns output dims (2*lane, 2*lane+1) ----
        // p_j broadcast via readlane (SGPR); whole wave reads V row (512 B).
        const float* vp0 = Vb + (size_t)pos0 * KVSTRIDE + lane * 2;
        #pragma unroll
        for (int bt = 0; bt < 4; ++bt) {
            #pragma unroll
            for (int jj = 0; jj < 16; ++jj) {
                const float pj = __uint_as_float(
                    __builtin_amdgcn_readlane(__float_as_uint(p[bt]), jj * 4));
                const float2 v2 =
                    *(const float2*)(vp0 + (size_t)(bt * 16 + jj) * KVSTRIDE);
                o0 += pj * v2.x;
                o1 += pj * v2.y;
            }
        }
    }

    // ---- write partial ----
    const int pidx = (bh * G_ + wave) * SPLIT_ + sp;
    o_ws[(size_t)pidx * DV_ + lane * 2]     = o0;
    o_ws[(size_t)pidx * DV_ + lane * 2 + 1] = o1;
    if (lane == 0) {
        ml_ws[pidx * 2]     = m;
        ml_ws[pidx * 2 + 1] = l;
    }
}

// ---------------------------------------------------------------------------
// Kernel 2: combine SPLIT partials per (b, h). One wave per output row.
// ---------------------------------------------------------------------------
__global__ __launch_bounds__(64)
void sfa_reduce(const float* __restrict__ o_ws,
                const float* __restrict__ ml_ws,
                float* __restrict__ out)
{
    const int bhg  = blockIdx.x;            // == b*H + h
    const int lane = threadIdx.x;

    float mv[SPLIT_], lv[SPLIT_];
    float mfull = -INFINITY;
    #pragma unroll
    for (int i = 0; i < SPLIT_; ++i) {
        mv[i] = ml_ws[(bhg * SPLIT_ + i) * 2];
        lv[i] = ml_ws[(bhg * SPLIT_ + i) * 2 + 1];
        mfull = fmaxf(mfull, mv[i]);
    }

    float o0 = 0.f, o1 = 0.f;
    if (mfull != -INFINITY) {
        float L = 0.f;
        #pragma unroll
        for (int i = 0; i < SPLIT_; ++i) {
            const float f = (mv[i] == -INFINITY)
                          ? 0.f
                          : __builtin_amdgcn_exp2f(mv[i] - mfull);
            L += lv[i] * f;
            const float* op = o_ws + (size_t)(bhg * SPLIT_ + i) * DV_ + lane * 2;
            o0 += f * op[0];
            o1 += f * op[1];
        }
        const float inv = 1.f / L;
        o0 *= inv;
        o1 *= inv;
    }
    out[(size_t)bhg * DV_ + lane * 2]     = o0;
    out[(size_t)bhg * DV_ + lane * 2 + 1] = o1;
}

// ---------------------------------------------------------------------------
extern "C" void kernel_launch(void* const* d_in, const int* in_sizes, int n_in,
                              void* d_out, int out_size, void* d_ws, size_t ws_size,
                              hipStream_t stream) {
    const float* q    = (const float*)d_in[0];
    const float* K    = (const float*)d_in[1];
    const float* V    = (const float*)d_in[2];
    const int*   bidx = (const int*)d_in[3];
    const int*   slen = (const int*)d_in[4];
    // d_in[5] = block_size (==BN_), compile-time constant here

    float* o_ws  = (float*)d_ws;                                   // 2.0 MB
    float* ml_ws = o_ws + (size_t)B_ * HKV_ * G_ * SPLIT_ * DV_;   // 32 KB

    sfa_partial<<<B_ * HKV_ * SPLIT_, 256, 0, stream>>>(
        q, K, V, bidx, slen, o_ws, ml_ws);

    sfa_reduce<<<B_ * H_, 64, 0, stream>>>(o_ws, ml_ws, (float*)d_out);
}

// Round 2
// 192.115 us; speedup vs baseline: 1.6198x; 1.6198x over previous
//
#include <hip/hip_runtime.h>
#include <math.h>

// Problem constants (from reference)
#define B_    16
#define H_    32
#define HKV_  8
#define G_    4      // H / HKV
#define D_    128
#define DV_   128
#define S_    8192
#define M_    64
#define BN_   64
#define KVSTRIDE (HKV_ * D_)            // 1024 floats between consecutive positions

// ---------------------------------------------------------------------------
// Kernel 1: per (b, hkv, split) partial flash-attention over M_/split KV
// blocks. 256 threads = 4 waves; wave w handles head g = w (4 GQA heads share
// the KV rows, served by L1/L2).
//
// QK lane layout: key j = (lane>>2) within a 16-key batch, dim "column"
// c = lane&3. Within-row byte offset = f*64 + c*16, so each 4-lane group
// reads one contiguous 64-B cache line -> 16 lines per 64-lane instruction
// (the coalescing floor), vs 64 lines with the c*128+f*16 layout.
// q slice kept in 32 VGPRs, pre-scaled by 1/sqrt(D)*log2(e) so softmax runs
// in the exp2 domain. No LDS, no barriers.
// ---------------------------------------------------------------------------
__global__ __launch_bounds__(256, 8)
void sfa_partial(const float* __restrict__ q,
                 const float* __restrict__ K,
                 const float* __restrict__ V,
                 const int*   __restrict__ blk_idx,
                 const int*   __restrict__ seqlens,
                 float* __restrict__ o_ws,    // [B*HKV*G*split][DV]
                 float* __restrict__ ml_ws,   // [B*HKV*G*split][2]
                 int split, int blk_per_split)
{
    const int wg  = blockIdx.x;            // (b*HKV + hkv)*split + sp
    const int sp  = wg % split;
    const int bh  = wg / split;            // b*HKV + hkv
    const int hkv = bh % HKV_;
    const int b   = bh / HKV_;

    const int tid  = threadIdx.x;
    const int wave = tid >> 6;              // == head-in-group g
    const int lane = tid & 63;
    const int c    = lane & 3;              // dim column (16 B within each 64-B line)
    const int jr   = lane >> 2;             // key index within 16-key batch

    const int h = hkv * G_ + wave;
    // 1/sqrt(128) * log2(e): scores land directly in exp2 domain
    const float kscale = 0.08838834764831845f * 1.4426950408889634f;

    // q4[f] = q[f*16 + c*4 .. +3], pre-scaled (8 float4 = 32 VGPR)
    float4 q4[8];
    {
        const float* qp = q + (size_t)(b * H_ + h) * D_ + c * 4;
        #pragma unroll
        for (int f = 0; f < 8; ++f) {
            float4 t = *(const float4*)(qp + f * 16);
            q4[f] = make_float4(t.x * kscale, t.y * kscale,
                                t.z * kscale, t.w * kscale);
        }
    }

    const int seqlen = seqlens[b];
    const int* bip = blk_idx + (b * HKV_ + hkv) * M_ + sp * blk_per_split;

    const float* Kb = K + (size_t)b * S_ * KVSTRIDE + hkv * D_;
    const float* Vb = V + (size_t)b * S_ * KVSTRIDE + hkv * D_;

    float m  = -INFINITY;   // running max (exp2 domain)
    float l  = 0.f;         // running sum of exp2
    float o0 = 0.f, o1 = 0.f;   // output dims 2*lane, 2*lane+1 (unnormalized)

    for (int bi = 0; bi < blk_per_split; ++bi) {
        const int blk = bip[bi];
        if (blk < 0) continue;              // invalid block: skip (uniform)
        const int pos0 = blk * BN_;

        // ---- QK^T: 64 scores for this wave's head ----
        float s[4];
        #pragma unroll
        for (int bt = 0; bt < 4; ++bt) {
            const int j   = bt * 16 + jr;
            const int pos = pos0 + j;
            const float* kp = Kb + (size_t)pos * KVSTRIDE + c * 4;
            float acc = 0.f;
            #pragma unroll
            for (int f = 0; f < 8; ++f) {
                float4 k4 = *(const float4*)(kp + f * 16);
                acc += q4[f].x * k4.x;
                acc += q4[f].y * k4.y;
                acc += q4[f].z * k4.z;
                acc += q4[f].w * k4.w;
            }
            // sum the 4 dim-columns (lanes c=0..3 of this key's group)
            acc += __shfl_xor(acc, 1);
            acc += __shfl_xor(acc, 2);
            s[bt] = (pos < seqlen) ? acc : -INFINITY;
        }

        // ---- block max (values already uniform within 4-lane groups) ----
        float bmax = fmaxf(fmaxf(s[0], s[1]), fmaxf(s[2], s[3]));
        #pragma unroll
        for (int off = 4; off < 64; off <<= 1)
            bmax = fmaxf(bmax, __shfl_xor(bmax, off));
        if (bmax == -INFINITY) continue;    // fully masked block

        const float newm = fmaxf(m, bmax);
        const float r = __builtin_amdgcn_exp2f(m - newm);  // m=-inf -> 0

        float p[4];
        float ps = 0.f;
        #pragma unroll
        for (int bt = 0; bt < 4; ++bt) {
            p[bt] = __builtin_amdgcn_exp2f(s[bt] - newm);  // masked -> 0
            ps += p[bt];
        }
        #pragma unroll
        for (int off = 4; off < 64; off <<= 1)
            ps += __shfl_xor(ps, off);

        l  = l * r + ps;
        o0 *= r;
        o1 *= r;
        m  = newm;

        // ---- PV: lane owns output dims (2*lane, 2*lane+1) ----
        // p_j broadcast via readlane (SGPR); whole wave reads V row (512 B,
        // 8 lines, fully coalesced).
        const float* vp0 = Vb + (size_t)pos0 * KVSTRIDE + lane * 2;
        #pragma unroll
        for (int bt = 0; bt < 4; ++bt) {
            #pragma unroll
            for (int jj = 0; jj < 16; ++jj) {
                const float pj = __uint_as_float(
                    __builtin_amdgcn_readlane(__float_as_uint(p[bt]), jj * 4));
                const float2 v2 =
                    *(const float2*)(vp0 + (size_t)(bt * 16 + jj) * KVSTRIDE);
                o0 += pj * v2.x;
                o1 += pj * v2.y;
            }
        }
    }

    // ---- write partial ----
    const int pidx = (bh * G_ + wave) * split + sp;
    o_ws[(size_t)pidx * DV_ + lane * 2]     = o0;
    o_ws[(size_t)pidx * DV_ + lane * 2 + 1] = o1;
    if (lane == 0) {
        ml_ws[pidx * 2]     = m;
        ml_ws[pidx * 2 + 1] = l;
    }
}

// ---------------------------------------------------------------------------
// Kernel 2: combine `split` partials per (b, h). One wave per output row.
// ml_ws is tiny (<=64 KB) and L2-hot; two passes are fine.
// ---------------------------------------------------------------------------
__global__ __launch_bounds__(64)
void sfa_reduce(const float* __restrict__ o_ws,
                const float* __restrict__ ml_ws,
                float* __restrict__ out,
                int split)
{
    const int bhg  = blockIdx.x;            // == b*H + h
    const int lane = threadIdx.x;

    float mfull = -INFINITY;
    for (int i = 0; i < split; ++i)
        mfull = fmaxf(mfull, ml_ws[(bhg * split + i) * 2]);

    float o0 = 0.f, o1 = 0.f;
    if (mfull != -INFINITY) {
        float L = 0.f;
        for (int i = 0; i < split; ++i) {
            const float mi = ml_ws[(bhg * split + i) * 2];
            const float li = ml_ws[(bhg * split + i) * 2 + 1];
            const float f = (mi == -INFINITY)
                          ? 0.f
                          : __builtin_amdgcn_exp2f(mi - mfull);
            L += li * f;
            const float* op = o_ws + (size_t)(bhg * split + i) * DV_ + lane * 2;
            o0 += f * op[0];
            o1 += f * op[1];
        }
        const float inv = 1.f / L;
        o0 *= inv;
        o1 *= inv;
    }
    out[(size_t)bhg * DV_ + lane * 2]     = o0;
    out[(size_t)bhg * DV_ + lane * 2 + 1] = o1;
}

// ---------------------------------------------------------------------------
extern "C" void kernel_launch(void* const* d_in, const int* in_sizes, int n_in,
                              void* d_out, int out_size, void* d_ws, size_t ws_size,
                              hipStream_t stream) {
    const float* q    = (const float*)d_in[0];
    const float* K    = (const float*)d_in[1];
    const float* V    = (const float*)d_in[2];
    const int*   bidx = (const int*)d_in[3];
    const int*   slen = (const int*)d_in[4];
    // d_in[5] = block_size (==BN_), compile-time constant here

    // Pick split by workspace: split=16 needs 4 MB + 64 KB.
    const size_t need16 = (size_t)B_ * HKV_ * G_ * 16 * (DV_ + 2) * sizeof(float);
    const int split = (ws_size >= need16) ? 16 : 8;
    const int blk_per_split = M_ / split;

    float* o_ws  = (float*)d_ws;
    float* ml_ws = o_ws + (size_t)B_ * HKV_ * G_ * split * DV_;

    sfa_partial<<<B_ * HKV_ * split, 256, 0, stream>>>(
        q, K, V, bidx, slen, o_ws, ml_ws, split, blk_per_split);

    sfa_reduce<<<B_ * H_, 64, 0, stream>>>(o_ws, ml_ws, (float*)d_out, split);
}

// Round 3
// 136.550 us; speedup vs baseline: 2.2790x; 1.4069x over previous
//
#include <hip/hip_runtime.h>
#include <math.h>

// Problem constants (from reference)
#define B_    16
#define H_    32
#define HKV_  8
#define G_    4      // H / HKV
#define D_    128
#define DV_   128
#define S_    8192
#define M_    64
#define BN_   64
#define KVSTRIDE (HKV_ * D_)            // 1024 floats between consecutive positions

// Async global->LDS, 16 B per lane. LDS dest must be wave-uniform base
// (HW writes base + lane*16); global src is per-lane.
__device__ __forceinline__ void gload_lds16(const float* gsrc, float* lds_dst) {
    __builtin_amdgcn_global_load_lds(
        (const __attribute__((address_space(1))) void*)gsrc,
        (__attribute__((address_space(3))) void*)lds_dst,
        16, 0, 0);
}

__device__ __forceinline__ float bcast_lane(float v, int srclane) {
    return __uint_as_float(__builtin_amdgcn_readlane(__float_as_uint(v), srclane));
}

// ---------------------------------------------------------------------------
// Kernel 1: per (b, hkv, split-chunk) partial attention over NBLK KV blocks.
// 256 threads = 4 waves; wave w = head g (4 GQA heads share the KV tile).
// Per block: the WG stages K (32 KB) + V (32 KB) into LDS ONCE via
// global_load_lds (64 x 1KB instrs, coalescing floor), then all 4 waves
// compute from LDS -> kills the 4x redundant global reads of R2.
//
// K LDS layout: 16B granule g of row r stored at slot (g ^ (r&7)) — swizzle
// applied on the GLOBAL source address (LDS dest stays linear, as required
// by global_load_lds). Makes the strided per-key ds_read_b128 QK reads
// bank-conflict-free. V stays linear (row-wide float2 reads are uniform).
// ---------------------------------------------------------------------------
template<int NBLK>
__global__ __launch_bounds__(256)
void sfa_partial(const float* __restrict__ q,
                 const float* __restrict__ K,
                 const float* __restrict__ V,
                 const int*   __restrict__ blk_idx,
                 const int*   __restrict__ seqlens,
                 float* __restrict__ o_ws,    // [B*HKV*G*split][DV]
                 float* __restrict__ ml_ws)   // [B*HKV*G*split][2]
{
    __shared__ float Klds[BN_ * D_];    // 32 KB, swizzled granules
    __shared__ float Vlds[BN_ * DV_];   // 32 KB, linear

    constexpr int split = M_ / NBLK;
    const int wg  = blockIdx.x;            // (b*HKV + hkv)*split + sp
    const int sp  = wg % split;
    const int bh  = wg / split;            // b*HKV + hkv
    const int hkv = bh % HKV_;
    const int b   = bh / HKV_;

    const int tid  = threadIdx.x;
    const int wave = tid >> 6;              // == head-in-group g
    const int lane = tid & 63;
    const int c    = lane & 3;              // dim column (16 B granule within 64 B)
    const int jr   = lane >> 2;             // key index within 16-key batch

    const int h = hkv * G_ + wave;
    // 1/sqrt(128) * log2(e): scores land directly in exp2 domain
    const float kscale = 0.08838834764831845f * 1.4426950408889634f;

    // q4[f] = q[f*16 + c*4 .. +3], pre-scaled (granule index g = f*4 + c)
    float4 q4[8];
    {
        const float* qp = q + (size_t)(b * H_ + h) * D_ + c * 4;
        #pragma unroll
        for (int f = 0; f < 8; ++f) {
            float4 t = *(const float4*)(qp + f * 16);
            q4[f] = make_float4(t.x * kscale, t.y * kscale,
                                t.z * kscale, t.w * kscale);
        }
    }

    const int seqlen = seqlens[b];
    const int* bip = blk_idx + (b * HKV_ + hkv) * M_ + sp * NBLK;

    const float* Kb = K + (size_t)b * S_ * KVSTRIDE + hkv * D_;
    const float* Vb = V + (size_t)b * S_ * KVSTRIDE + hkv * D_;

    float m  = -INFINITY;
    float l  = 0.f;
    float o0 = 0.f, o1 = 0.f;   // output dims 2*lane, 2*lane+1 (unnormalized)

    for (int bi = 0; bi < NBLK; ++bi) {
        const int blk = bip[bi];            // WG-uniform
        if (blk < 0) continue;
        const int pos0 = blk * BN_;

        if (bi > 0) __syncthreads();        // LDS reuse guard (uniform branch)

        // ---- stage K+V tile: each wave issues 8+8 global_load_lds of 1 KB.
        // Instr p covers rows {2p, 2p+1}; lane l -> row 2p + (l>>5),
        // granule slot l&31.
        #pragma unroll
        for (int i = 0; i < 8; ++i) {
            const int p   = wave * 8 + i;           // 0..31
            const int row = p * 2 + (lane >> 5);
            const int g16 = lane & 31;
            const float* src = Kb + (size_t)(pos0 + row) * KVSTRIDE
                                  + ((g16 ^ (row & 7)) << 2);
            gload_lds16(src, Klds + p * 256);
        }
        #pragma unroll
        for (int i = 0; i < 8; ++i) {
            const int p   = wave * 8 + i;
            const int row = p * 2 + (lane >> 5);
            const int g16 = lane & 31;
            const float* src = Vb + (size_t)(pos0 + row) * KVSTRIDE
                                  + (g16 << 2);
            gload_lds16(src, Vlds + p * 256);
        }
        __syncthreads();                    // waits vmcnt(0) + barrier

        // ---- QK^T from LDS: 64 scores for this wave's head ----
        float s[4];
        #pragma unroll
        for (int bt = 0; bt < 4; ++bt) {
            const int r   = bt * 16 + jr;
            const int pos = pos0 + r;
            const float* kr = Klds + r * D_;
            float acc = 0.f;
            #pragma unroll
            for (int f = 0; f < 8; ++f) {
                const int gg = (((f * 4 + c) ^ (r & 7)) << 2);
                float4 k4 = *(const float4*)(kr + gg);
                acc += q4[f].x * k4.x;
                acc += q4[f].y * k4.y;
                acc += q4[f].z * k4.z;
                acc += q4[f].w * k4.w;
            }
            acc += __shfl_xor(acc, 1);
            acc += __shfl_xor(acc, 2);
            s[bt] = (pos < seqlen) ? acc : -INFINITY;
        }

        // ---- block max (uniform within 4-lane groups) ----
        float bmax = fmaxf(fmaxf(s[0], s[1]), fmaxf(s[2], s[3]));
        #pragma unroll
        for (int off = 4; off < 64; off <<= 1)
            bmax = fmaxf(bmax, __shfl_xor(bmax, off));
        if (bmax == -INFINITY) continue;    // fully masked block

        const float newm = fmaxf(m, bmax);
        const float r = __builtin_amdgcn_exp2f(m - newm);  // m=-inf -> 0

        float p[4];
        float ps = 0.f;
        #pragma unroll
        for (int bt = 0; bt < 4; ++bt) {
            p[bt] = __builtin_amdgcn_exp2f(s[bt] - newm);  // masked -> 0
            ps += p[bt];
        }
        #pragma unroll
        for (int off = 4; off < 64; off <<= 1)
            ps += __shfl_xor(ps, off);

        l  = l * r + ps;
        o0 *= r;
        o1 *= r;
        m  = newm;

        // ---- PV from LDS: lane owns dims (2*lane, 2*lane+1) ----
        const float* vp0 = Vlds + lane * 2;
        #pragma unroll
        for (int bt = 0; bt < 4; ++bt) {
            #pragma unroll
            for (int jj = 0; jj < 16; ++jj) {
                const float pj = bcast_lane(p[bt], jj * 4);
                const float2 v2 = *(const float2*)(vp0 + (bt * 16 + jj) * DV_);
                o0 += pj * v2.x;
                o1 += pj * v2.y;
            }
        }
    }

    // ---- write partial ----
    const int pidx = (bh * G_ + wave) * split + sp;
    o_ws[(size_t)pidx * DV_ + lane * 2]     = o0;
    o_ws[(size_t)pidx * DV_ + lane * 2 + 1] = o1;
    if (lane == 0) {
        ml_ws[pidx * 2]     = m;
        ml_ws[pidx * 2 + 1] = l;
    }
}

// ---------------------------------------------------------------------------
// Kernel 2: combine SPLIT partials per (b, h). One wave per output row;
// lane sp holds (m,l) of partial sp, factors broadcast via readlane.
// ---------------------------------------------------------------------------
template<int SPLIT>
__global__ __launch_bounds__(64)
void sfa_reduce(const float* __restrict__ o_ws,
                const float* __restrict__ ml_ws,
                float* __restrict__ out)
{
    const int bhg  = blockIdx.x;            // == b*H + h
    const int lane = threadIdx.x;

    float mi = -INFINITY, li = 0.f;
    if (lane < SPLIT) {
        const float2 t = ((const float2*)ml_ws)[bhg * SPLIT + lane];
        mi = t.x; li = t.y;
    }
    float mfull = mi;
    #pragma unroll
    for (int off = 1; off < 64; off <<= 1)
        mfull = fmaxf(mfull, __shfl_xor(mfull, off));

    const float f = (mi == -INFINITY) ? 0.f
                  : __builtin_amdgcn_exp2f(mi - mfull);
    float L = li * f;
    #pragma unroll
    for (int off = 1; off < 64; off <<= 1)
        L += __shfl_xor(L, off);

    float o0 = 0.f, o1 = 0.f;
    #pragma unroll 8
    for (int i = 0; i < SPLIT; ++i) {
        const float fi = bcast_lane(f, i);  // uniform
        if (fi != 0.f) {
            const float* op = o_ws + (size_t)(bhg * SPLIT + i) * DV_ + lane * 2;
            o0 += fi * op[0];
            o1 += fi * op[1];
        }
    }
    const float inv = (L > 0.f) ? (1.f / L) : 0.f;
    out[(size_t)bhg * DV_ + lane * 2]     = o0 * inv;
    out[(size_t)bhg * DV_ + lane * 2 + 1] = o1 * inv;
}

// ---------------------------------------------------------------------------
extern "C" void kernel_launch(void* const* d_in, const int* in_sizes, int n_in,
                              void* d_out, int out_size, void* d_ws, size_t ws_size,
                              hipStream_t stream) {
    const float* q    = (const float*)d_in[0];
    const float* K    = (const float*)d_in[1];
    const float* V    = (const float*)d_in[2];
    const int*   bidx = (const int*)d_in[3];
    const int*   slen = (const int*)d_in[4];
    // d_in[5] = block_size (==BN_), compile-time constant here

    const size_t need64 = (size_t)B_ * HKV_ * G_ * 64 * (DV_ + 2) * sizeof(float);
    if (ws_size >= need64) {
        // split = 64: one KV block per WG
        float* o_ws  = (float*)d_ws;                                   // 16.8 MB
        float* ml_ws = o_ws + (size_t)B_ * HKV_ * G_ * 64 * DV_;       // 256 KB
        sfa_partial<1><<<B_ * HKV_ * 64, 256, 0, stream>>>(
            q, K, V, bidx, slen, o_ws, ml_ws);
        sfa_reduce<64><<<B_ * H_, 64, 0, stream>>>(o_ws, ml_ws, (float*)d_out);
    } else {
        // fallback split = 8 (2.1 MB workspace)
        float* o_ws  = (float*)d_ws;
        float* ml_ws = o_ws + (size_t)B_ * HKV_ * G_ * 8 * DV_;
        sfa_partial<8><<<B_ * HKV_ * 8, 256, 0, stream>>>(
            q, K, V, bidx, slen, o_ws, ml_ws);
        sfa_reduce<8><<<B_ * H_, 64, 0, stream>>>(o_ws, ml_ws, (float*)d_out);
    }
}

// Round 4
// 98.007 us; speedup vs baseline: 3.1752x; 1.3933x over previous
//
#include <hip/hip_runtime.h>
#include <math.h>

// Problem constants (from reference)
#define B_    16
#define H_    32
#define HKV_  8
#define G_    4      // H / HKV
#define D_    128
#define DV_   128
#define S_    8192
#define M_    64
#define BN_   64
#define KVSTRIDE (HKV_ * D_)     // 1024 floats between consecutive positions

#define CHUNK_ 32                // rows per pipeline chunk (half a KV block)
#define NBLK_  4                 // KV blocks per WG
#define NC_    (NBLK_ * 2)       // chunks per WG
#define SPLIT_ (M_ / NBLK_)      // 16 partials per (b,hkv)

// Async global->LDS, 16 B per lane: LDS dest is wave-uniform base + lane*16,
// global src is per-lane (swizzle goes on the SOURCE address).
__device__ __forceinline__ void gload_lds16(const float* gsrc, float* lds_dst) {
    __builtin_amdgcn_global_load_lds(
        (const __attribute__((address_space(1))) void*)gsrc,
        (__attribute__((address_space(3))) void*)lds_dst,
        16, 0, 0);
}

__device__ __forceinline__ float bcast_lane(float v, int srclane) {
    return __uint_as_float(__builtin_amdgcn_readlane(__float_as_uint(v), srclane));
}

// ---------------------------------------------------------------------------
// Kernel 1: per (b, hkv, sp) partial attention over NBLK_ KV blocks,
// software-pipelined at 32-row chunk granularity with counted vmcnt waits
// (loads stay in flight across barriers; vmcnt never drains to 0 in the
// steady state). 256 threads = 4 waves; wave w = head g.
//
// Per-wave issue schedule (4 loads per stage group):
//   prologue: K0 V0 K1                       (12 outstanding)
//   iter ci : wait vmcnt(8)  -> K[ci] done   -> barrier -> QK(K[ci])
//             issue V[ci+1]
//             wait vmcnt(8)  -> V[ci] done   -> barrier
//             issue K[ci+2]  -> softmax + PV(V[ci])
// Buffer-overwrite safety: each stage targets the buffer last READ two
// barriers earlier (verified per-phase).
// ---------------------------------------------------------------------------
__global__ __launch_bounds__(256)
void sfa_partial(const float* __restrict__ q,
                 const float* __restrict__ K,
                 const float* __restrict__ V,
                 const int*   __restrict__ blk_idx,
                 const int*   __restrict__ seqlens,
                 float* __restrict__ o_ws,    // [B*HKV*G*SPLIT_][DV]
                 float* __restrict__ ml_ws)   // [B*HKV*G*SPLIT_][2]
{
    __shared__ float Klds[2][CHUNK_ * D_];   // 2 x 16 KB, swizzled granules
    __shared__ float Vlds[2][CHUNK_ * DV_];  // 2 x 16 KB, linear

    const int wg  = blockIdx.x;            // (b*HKV + hkv)*SPLIT_ + sp
    const int sp  = wg % SPLIT_;
    const int bh  = wg / SPLIT_;
    const int hkv = bh % HKV_;
    const int b   = bh / HKV_;

    const int tid  = threadIdx.x;
    const int wave = tid >> 6;              // == head-in-group g
    const int lane = tid & 63;
    const int c    = lane & 3;              // 16-B granule column within 64 B
    const int jr   = lane >> 2;             // key index within 16-key batch

    const int h = hkv * G_ + wave;
    // 1/sqrt(128) * log2(e): scores land directly in exp2 domain
    const float kscale = 0.08838834764831845f * 1.4426950408889634f;

    // q4[f] = q[f*16 + c*4 .. +3], pre-scaled (granule index g = f*4 + c)
    float4 q4[8];
    {
        const float* qp = q + (size_t)(b * H_ + h) * D_ + c * 4;
        #pragma unroll
        for (int f = 0; f < 8; ++f) {
            float4 t = *(const float4*)(qp + f * 16);
            q4[f] = make_float4(t.x * kscale, t.y * kscale,
                                t.z * kscale, t.w * kscale);
        }
    }

    const int seqlen = seqlens[b];
    int blks[NBLK_];
    {
        const int* bip = blk_idx + (b * HKV_ + hkv) * M_ + sp * NBLK_;
        #pragma unroll
        for (int i = 0; i < NBLK_; ++i) blks[i] = bip[i];
    }

    const float* Kb = K + (size_t)b * S_ * KVSTRIDE + hkv * D_;
    const float* Vb = V + (size_t)b * S_ * KVSTRIDE + hkv * D_;

    // Drain all prologue vector loads so the counted vmcnt waits are exact.
    asm volatile("s_waitcnt vmcnt(0)" ::: "memory");

    // Stage one 32-row chunk of K (16 KB): 4 instrs/wave, 1 KB each.
    // Instr p covers rows {2p, 2p+1}; lane -> row 2p+(lane>>5), slot lane&31.
    // K granule slot = global granule ^ (row&7)  (conflict-free ds_read_b128).
    auto stageK = [&](int ci) {
        const int blk  = blks[ci >> 1];
        const int blkc = (blk < 0) ? 0 : blk;          // clamp: keep loads legal
        const size_t rowbase = (size_t)blkc * BN_ + (ci & 1) * CHUNK_;
        float* dst = &Klds[ci & 1][0];
        #pragma unroll
        for (int i = 0; i < 4; ++i) {
            const int p   = wave * 4 + i;              // 0..15
            const int row = 2 * p + (lane >> 5);       // 0..31
            const int g16 = lane & 31;
            const float* src = Kb + (rowbase + row) * KVSTRIDE
                                  + ((g16 ^ (row & 7)) << 2);
            gload_lds16(src, dst + p * 256);
        }
    };
    auto stageV = [&](int ci) {
        const int blk  = blks[ci >> 1];
        const int blkc = (blk < 0) ? 0 : blk;
        const size_t rowbase = (size_t)blkc * BN_ + (ci & 1) * CHUNK_;
        float* dst = &Vlds[ci & 1][0];
        #pragma unroll
        for (int i = 0; i < 4; ++i) {
            const int p   = wave * 4 + i;
            const int row = 2 * p + (lane >> 5);
            const int g16 = lane & 31;
            const float* src = Vb + (rowbase + row) * KVSTRIDE + (g16 << 2);
            gload_lds16(src, dst + p * 256);
        }
    };

    float m  = -INFINITY;
    float l  = 0.f;
    float o0 = 0.f, o1 = 0.f;   // output dims 2*lane, 2*lane+1 (unnormalized)

    stageK(0); stageV(0); stageK(1);

    #pragma unroll
    for (int ci = 0; ci < NC_; ++ci) {
        const int blk    = blks[ci >> 1];
        const bool bval  = (blk >= 0);
        const int  pos0  = ((blk < 0) ? 0 : blk) * BN_ + (ci & 1) * CHUNK_;

        // ---- K[ci] ready ----
        if (ci < NC_ - 1) asm volatile("s_waitcnt vmcnt(8)" ::: "memory");
        else              asm volatile("s_waitcnt vmcnt(4)" ::: "memory");
        __builtin_amdgcn_s_barrier();
        __builtin_amdgcn_sched_barrier(0);

        // ---- QK^T from LDS: 32 scores for this wave's head ----
        float s[2];
        #pragma unroll
        for (int bt = 0; bt < 2; ++bt) {
            const int r = bt * 16 + jr;
            const float* kr = &Klds[ci & 1][r * D_];
            float acc = 0.f;
            #pragma unroll
            for (int f = 0; f < 8; ++f) {
                const int gg = (((f * 4 + c) ^ (r & 7)) << 2);
                float4 k4 = *(const float4*)(kr + gg);
                acc += q4[f].x * k4.x;
                acc += q4[f].y * k4.y;
                acc += q4[f].z * k4.z;
                acc += q4[f].w * k4.w;
            }
            acc += __shfl_xor(acc, 1);
            acc += __shfl_xor(acc, 2);
            s[bt] = (bval && (pos0 + r) < seqlen) ? acc : -INFINITY;
        }

        if (ci + 1 < NC_) stageV(ci + 1);

        // ---- V[ci] ready ----
        if (ci < NC_ - 1) asm volatile("s_waitcnt vmcnt(8)" ::: "memory");
        else              asm volatile("s_waitcnt vmcnt(0)" ::: "memory");
        __builtin_amdgcn_s_barrier();
        __builtin_amdgcn_sched_barrier(0);

        if (ci + 2 < NC_) stageK(ci + 2);

        // ---- online softmax (exp2 domain) ----
        float bmax = fmaxf(s[0], s[1]);
        #pragma unroll
        for (int off = 4; off < 64; off <<= 1)
            bmax = fmaxf(bmax, __shfl_xor(bmax, off));

        const float newm = fmaxf(m, bmax);
        if (newm != -INFINITY) {            // wave-uniform; no barriers inside
            const float rr = __builtin_amdgcn_exp2f(m - newm);   // m=-inf -> 0
            const float p0 = __builtin_amdgcn_exp2f(s[0] - newm);
            const float p1 = __builtin_amdgcn_exp2f(s[1] - newm);
            float ps = p0 + p1;
            #pragma unroll
            for (int off = 4; off < 64; off <<= 1)
                ps += __shfl_xor(ps, off);

            l  = l * rr + ps;
            o0 *= rr;
            o1 *= rr;
            m  = newm;

            // ---- PV from LDS: lane owns dims (2*lane, 2*lane+1) ----
            const float* vp0 = &Vlds[ci & 1][lane * 2];
            #pragma unroll
            for (int jj = 0; jj < 16; ++jj) {
                const float pj = bcast_lane(p0, jj * 4);
                const float2 v2 = *(const float2*)(vp0 + jj * DV_);
                o0 += pj * v2.x;
                o1 += pj * v2.y;
            }
            #pragma unroll
            for (int jj = 0; jj < 16; ++jj) {
                const float pj = bcast_lane(p1, jj * 4);
                const float2 v2 = *(const float2*)(vp0 + (16 + jj) * DV_);
                o0 += pj * v2.x;
                o1 += pj * v2.y;
            }
        }
    }

    // ---- write partial ----
    const int pidx = (bh * G_ + wave) * SPLIT_ + sp;
    o_ws[(size_t)pidx * DV_ + lane * 2]     = o0;
    o_ws[(size_t)pidx * DV_ + lane * 2 + 1] = o1;
    if (lane == 0) {
        ml_ws[pidx * 2]     = m;
        ml_ws[pidx * 2 + 1] = l;
    }
}

// ---------------------------------------------------------------------------
// Kernel 2: combine SPLIT partials per (b, h). One wave per output row;
// lane sp holds (m,l) of partial sp, factors broadcast via readlane.
// ---------------------------------------------------------------------------
template<int SPLIT>
__global__ __launch_bounds__(64)
void sfa_reduce(const float* __restrict__ o_ws,
                const float* __restrict__ ml_ws,
                float* __restrict__ out)
{
    const int bhg  = blockIdx.x;            // == b*H + h
    const int lane = threadIdx.x;

    float mi = -INFINITY, li = 0.f;
    if (lane < SPLIT) {
        const float2 t = ((const float2*)ml_ws)[bhg * SPLIT + lane];
        mi = t.x; li = t.y;
    }
    float mfull = mi;
    #pragma unroll
    for (int off = 1; off < 64; off <<= 1)
        mfull = fmaxf(mfull, __shfl_xor(mfull, off));

    const float f = (mi == -INFINITY) ? 0.f
                  : __builtin_amdgcn_exp2f(mi - mfull);
    float L = li * f;
    #pragma unroll
    for (int off = 1; off < 64; off <<= 1)
        L += __shfl_xor(L, off);

    float o0 = 0.f, o1 = 0.f;
    #pragma unroll
    for (int i = 0; i < SPLIT; ++i) {
        const float fi = bcast_lane(f, i);  // uniform
        if (fi != 0.f) {
            const float* op = o_ws + (size_t)(bhg * SPLIT + i) * DV_ + lane * 2;
            o0 += fi * op[0];
            o1 += fi * op[1];
        }
    }
    const float inv = (L > 0.f) ? (1.f / L) : 0.f;
    out[(size_t)bhg * DV_ + lane * 2]     = o0 * inv;
    out[(size_t)bhg * DV_ + lane * 2 + 1] = o1 * inv;
}

// ---------------------------------------------------------------------------
extern "C" void kernel_launch(void* const* d_in, const int* in_sizes, int n_in,
                              void* d_out, int out_size, void* d_ws, size_t ws_size,
                              hipStream_t stream) {
    const float* q    = (const float*)d_in[0];
    const float* K    = (const float*)d_in[1];
    const float* V    = (const float*)d_in[2];
    const int*   bidx = (const int*)d_in[3];
    const int*   slen = (const int*)d_in[4];
    // d_in[5] = block_size (==BN_), compile-time constant here

    // ws need: 16*8*4*16*128 floats (4 MB) + 64 KB of (m,l)
    float* o_ws  = (float*)d_ws;
    float* ml_ws = o_ws + (size_t)B_ * HKV_ * G_ * SPLIT_ * DV_;

    sfa_partial<<<B_ * HKV_ * SPLIT_, 256, 0, stream>>>(
        q, K, V, bidx, slen, o_ws, ml_ws);

    sfa_reduce<SPLIT_><<<B_ * H_, 64, 0, stream>>>(o_ws, ml_ws, (float*)d_out);
}

// Round 5
// 93.637 us; speedup vs baseline: 3.3234x; 1.0467x over previous
//
#include <hip/hip_runtime.h>
#include <math.h>

// Problem constants (from reference)
#define B_    16
#define H_    32
#define HKV_  8
#define G_    4      // H / HKV
#define D_    128
#define DV_   128
#define S_    8192
#define M_    64
#define BN_   64
#define KVSTRIDE (HKV_ * D_)     // 1024 floats between consecutive positions

#define CHUNK_ 32                // rows per pipeline chunk (half a KV block)
#define NBLK_  4                 // KV blocks per work item
#define SPLIT_ (M_ / NBLK_)      // 16 partials per (b,hkv)
#define ITEMS_ 4                 // work items per WG (same bh, sp quadrant)
#define NCTOT_ (ITEMS_ * NBLK_ * 2)   // 32 chunks per WG

// Async global->LDS, 16 B per lane: LDS dest is wave-uniform base + lane*16,
// global src is per-lane (swizzle goes on the SOURCE address).
__device__ __forceinline__ void gload_lds16(const float* gsrc, float* lds_dst) {
    __builtin_amdgcn_global_load_lds(
        (const __attribute__((address_space(1))) void*)gsrc,
        (__attribute__((address_space(3))) void*)lds_dst,
        16, 0, 0);
}

__device__ __forceinline__ float bcast_lane(float v, int srclane) {
    return __uint_as_float(__builtin_amdgcn_readlane(__float_as_uint(v), srclane));
}

// ---------------------------------------------------------------------------
// Kernel 1: persistent WGs. 512 WGs (all co-resident at 2/CU); WG handles
// ITEMS_=4 work items of the SAME (b,hkv) — sp = quad*4+{0..3} — so q and
// the 16 block ids load once, and the counted-vmcnt chunk pipeline runs
// continuously across item boundaries (no mid-kernel drains).
//
// XCD grouping: all 4 WGs of one bh get blockIdx.x % 8 == bh % 8 (round-robin
// blockIdx->XCD), so duplicate block ids within a (b,hkv) hit that XCD's L2.
//
// Per-wave steady-state schedule (4 loads per stage group, 3 groups = 12 KB
// in flight): wait vmcnt(8) -> barrier -> QK(K[cc]) ; issue V[cc+1] ;
// wait vmcnt(8) -> barrier -> issue K[cc+2] ; softmax+PV(V[cc]).
// Partial stores at item boundaries enter the vmcnt stream; traced: they
// cause a <=2-op transient overwait, never an underwait. Last chunk uses
// drain counts 4 / 0.
// ---------------------------------------------------------------------------
__global__ __launch_bounds__(256)
void sfa_partial(const float* __restrict__ q,
                 const float* __restrict__ K,
                 const float* __restrict__ V,
                 const int*   __restrict__ blk_idx,
                 const int*   __restrict__ seqlens,
                 float* __restrict__ o_ws,    // [B*HKV*G*SPLIT_][DV]
                 float* __restrict__ ml_ws)   // [B*HKV*G*SPLIT_][2]
{
    __shared__ float Klds[2][CHUNK_ * D_];   // 2 x 16 KB, swizzled granules
    __shared__ float Vlds[2][CHUNK_ * DV_];  // 2 x 16 KB, linear

    const int w    = blockIdx.x;        // 0..511
    const int t    = w >> 3;            // 0..63
    const int bh   = (w & 7) + 8 * (t & 15);   // 0..127, bh%8 == w%8
    const int quad = t >> 4;            // 0..3  (sp quadrant)
    const int hkv  = bh & 7;
    const int b    = bh >> 3;

    const int tid  = threadIdx.x;
    const int wave = tid >> 6;          // == head-in-group g
    const int lane = tid & 63;
    const int c    = lane & 3;          // 16-B granule column within 64 B
    const int jr   = lane >> 2;         // key index within 16-key batch

    const int h = hkv * G_ + wave;
    // 1/sqrt(128) * log2(e): scores land directly in exp2 domain
    const float kscale = 0.08838834764831845f * 1.4426950408889634f;

    // q4[f] = q[f*16 + c*4 .. +3], pre-scaled (granule index g = f*4 + c)
    float4 q4[8];
    {
        const float* qp = q + (size_t)(b * H_ + h) * D_ + c * 4;
        #pragma unroll
        for (int f = 0; f < 8; ++f) {
            float4 tq = *(const float4*)(qp + f * 16);
            q4[f] = make_float4(tq.x * kscale, tq.y * kscale,
                                tq.z * kscale, tq.w * kscale);
        }
    }

    // 16 block ids (4 items x 4 blocks), contiguous span, parked in lanes 0-15
    int vblk = 0;
    if (lane < 16) vblk = blk_idx[bh * M_ + quad * 16 + lane];

    const int seqlen = seqlens[b];
    const float* Kb = K + (size_t)b * S_ * KVSTRIDE + hkv * D_;
    const float* Vb = V + (size_t)b * S_ * KVSTRIDE + hkv * D_;

    // Drain prologue loads so the counted vmcnt waits start exact.
    asm volatile("s_waitcnt vmcnt(0)" ::: "memory");

    // Stage one 32-row chunk (16 KB): 4 instrs/wave, 1 KB each.
    // Instr p covers rows {2p, 2p+1}; lane -> row 2p+(lane>>5), slot lane&31.
    // K source granule = slot ^ (row&7)  (conflict-free ds_read_b128 later).
    auto stageK = [&](int cc, int blk) {
        const int blkc = (blk < 0) ? 0 : blk;          // clamp: loads stay legal
        const size_t rowbase = (size_t)blkc * BN_ + (cc & 1) * CHUNK_;
        float* dst = &Klds[cc & 1][0];
        #pragma unroll
        for (int i = 0; i < 4; ++i) {
            const int p   = wave * 4 + i;              // 0..15
            const int row = 2 * p + (lane >> 5);       // 0..31
            const int g16 = lane & 31;
            const float* src = Kb + (rowbase + row) * KVSTRIDE
                                  + ((g16 ^ (row & 7)) << 2);
            gload_lds16(src, dst + p * 256);
        }
    };
    auto stageV = [&](int cc, int blk) {
        const int blkc = (blk < 0) ? 0 : blk;
        const size_t rowbase = (size_t)blkc * BN_ + (cc & 1) * CHUNK_;
        float* dst = &Vlds[cc & 1][0];
        #pragma unroll
        for (int i = 0; i < 4; ++i) {
            const int p   = wave * 4 + i;
            const int row = 2 * p + (lane >> 5);
            const int g16 = lane & 31;
            const float* src = Vb + (rowbase + row) * KVSTRIDE + (g16 << 2);
            gload_lds16(src, dst + p * 256);
        }
    };
    // block id of chunk cc (index cc>>1 in the 16-entry list), uniform
    auto blkOf = [&](int cc) -> int {
        return __builtin_amdgcn_readlane(vblk, cc >> 1);
    };

    float m  = -INFINITY;
    float l  = 0.f;
    float o0 = 0.f, o1 = 0.f;   // output dims 2*lane, 2*lane+1 (unnormalized)

    stageK(0, blkOf(0));
    stageV(0, blkOf(0));
    stageK(1, blkOf(1));

    #pragma unroll 1
    for (int item = 0; item < ITEMS_; ++item) {
        #pragma unroll
        for (int ci = 0; ci < 8; ++ci) {
            const int  cc   = item * 8 + ci;
            const int  blk  = blkOf(cc);
            const bool bval = (blk >= 0);
            const int  pos0 = ((blk < 0) ? 0 : blk) * BN_ + (cc & 1) * CHUNK_;
            const bool last = (cc == NCTOT_ - 1);

            // ---- K[cc] ready ----
            if (last) asm volatile("s_waitcnt vmcnt(4)" ::: "memory");
            else      asm volatile("s_waitcnt vmcnt(8)" ::: "memory");
            __builtin_amdgcn_s_barrier();
            __builtin_amdgcn_sched_barrier(0);

            // ---- QK^T from LDS: 32 scores for this wave's head ----
            float s[2];
            #pragma unroll
            for (int bt = 0; bt < 2; ++bt) {
                const int r = bt * 16 + jr;
                const float* kr = &Klds[cc & 1][r * D_];
                float acc = 0.f;
                #pragma unroll
                for (int f = 0; f < 8; ++f) {
                    const int gg = (((f * 4 + c) ^ (r & 7)) << 2);
                    float4 k4 = *(const float4*)(kr + gg);
                    acc += q4[f].x * k4.x;
                    acc += q4[f].y * k4.y;
                    acc += q4[f].z * k4.z;
                    acc += q4[f].w * k4.w;
                }
                acc += __shfl_xor(acc, 1);
                acc += __shfl_xor(acc, 2);
                s[bt] = (bval && (pos0 + r) < seqlen) ? acc : -INFINITY;
            }

            if (cc + 1 < NCTOT_) stageV(cc + 1, blkOf(cc + 1));

            // ---- V[cc] ready ----
            if (last) asm volatile("s_waitcnt vmcnt(0)" ::: "memory");
            else      asm volatile("s_waitcnt vmcnt(8)" ::: "memory");
            __builtin_amdgcn_s_barrier();
            __builtin_amdgcn_sched_barrier(0);

            if (cc + 2 < NCTOT_) stageK(cc + 2, blkOf(cc + 2));

            // ---- online softmax (exp2 domain) ----
            float bmax = fmaxf(s[0], s[1]);
            #pragma unroll
            for (int off = 4; off < 64; off <<= 1)
                bmax = fmaxf(bmax, __shfl_xor(bmax, off));

            const float newm = fmaxf(m, bmax);
            if (newm != -INFINITY) {        // wave-uniform; no barriers inside
                const float rr = __builtin_amdgcn_exp2f(m - newm);
                const float p0 = __builtin_amdgcn_exp2f(s[0] - newm);
                const float p1 = __builtin_amdgcn_exp2f(s[1] - newm);
                float ps = p0 + p1;
                #pragma unroll
                for (int off = 4; off < 64; off <<= 1)
                    ps += __shfl_xor(ps, off);

                l  = l * rr + ps;
                o0 *= rr;
                o1 *= rr;
                m  = newm;

                // ---- PV from LDS: lane owns dims (2*lane, 2*lane+1) ----
                const float* vp0 = &Vlds[cc & 1][lane * 2];
                #pragma unroll
                for (int jj = 0; jj < 16; ++jj) {
                    const float pj = bcast_lane(p0, jj * 4);
                    const float2 v2 = *(const float2*)(vp0 + jj * DV_);
                    o0 += pj * v2.x;
                    o1 += pj * v2.y;
                }
                #pragma unroll
                for (int jj = 0; jj < 16; ++jj) {
                    const float pj = bcast_lane(p1, jj * 4);
                    const float2 v2 = *(const float2*)(vp0 + (16 + jj) * DV_);
                    o0 += pj * v2.x;
                    o1 += pj * v2.y;
                }
            }

            // ---- item boundary: write partial, reset state ----
            if (ci == 7) {
                const int sp   = quad * ITEMS_ + item;
                const int pidx = (bh * G_ + wave) * SPLIT_ + sp;
                *(float2*)(o_ws + (size_t)pidx * DV_ + lane * 2) =
                    make_float2(o0, o1);
                if (lane == 0)
                    *(float2*)(ml_ws + pidx * 2) = make_float2(m, l);
                m = -INFINITY; l = 0.f; o0 = 0.f; o1 = 0.f;
            }
        }
    }
}

// ---------------------------------------------------------------------------
// Kernel 2: combine SPLIT partials per (b, h). One wave per output row;
// lane sp holds (m,l) of partial sp, factors broadcast via readlane.
// ---------------------------------------------------------------------------
template<int SPLIT>
__global__ __launch_bounds__(64)
void sfa_reduce(const float* __restrict__ o_ws,
                const float* __restrict__ ml_ws,
                float* __restrict__ out)
{
    const int bhg  = blockIdx.x;            // == b*H + h
    const int lane = threadIdx.x;

    float mi = -INFINITY, li = 0.f;
    if (lane < SPLIT) {
        const float2 t = ((const float2*)ml_ws)[bhg * SPLIT + lane];
        mi = t.x; li = t.y;
    }
    float mfull = mi;
    #pragma unroll
    for (int off = 1; off < 64; off <<= 1)
        mfull = fmaxf(mfull, __shfl_xor(mfull, off));

    const float f = (mi == -INFINITY) ? 0.f
                  : __builtin_amdgcn_exp2f(mi - mfull);
    float L = li * f;
    #pragma unroll
    for (int off = 1; off < 64; off <<= 1)
        L += __shfl_xor(L, off);

    float o0 = 0.f, o1 = 0.f;
    #pragma unroll
    for (int i = 0; i < SPLIT; ++i) {
        const float fi = bcast_lane(f, i);  // uniform
        if (fi != 0.f) {
            const float* op = o_ws + (size_t)(bhg * SPLIT + i) * DV_ + lane * 2;
            o0 += fi * op[0];
            o1 += fi * op[1];
        }
    }
    const float inv = (L > 0.f) ? (1.f / L) : 0.f;
    out[(size_t)bhg * DV_ + lane * 2]     = o0 * inv;
    out[(size_t)bhg * DV_ + lane * 2 + 1] = o1 * inv;
}

// ---------------------------------------------------------------------------
extern "C" void kernel_launch(void* const* d_in, const int* in_sizes, int n_in,
                              void* d_out, int out_size, void* d_ws, size_t ws_size,
                              hipStream_t stream) {
    const float* q    = (const float*)d_in[0];
    const float* K    = (const float*)d_in[1];
    const float* V    = (const float*)d_in[2];
    const int*   bidx = (const int*)d_in[3];
    const int*   slen = (const int*)d_in[4];
    // d_in[5] = block_size (==BN_), compile-time constant here

    // ws need: 16*8*4*16*128 floats (4.19 MB) + 64 KB of (m,l)
    float* o_ws  = (float*)d_ws;
    float* ml_ws = o_ws + (size_t)B_ * HKV_ * G_ * SPLIT_ * DV_;

    sfa_partial<<<B_ * HKV_ * SPLIT_ / ITEMS_, 256, 0, stream>>>(
        q, K, V, bidx, slen, o_ws, ml_ws);

    sfa_reduce<SPLIT_><<<B_ * H_, 64, 0, stream>>>(o_ws, ml_ws, (float*)d_out);
}

// Round 6
// 88.727 us; speedup vs baseline: 3.5073x; 1.0553x over previous
//
#include <hip/hip_runtime.h>
#include <math.h>

// Problem constants (from reference)
#define B_    16
#define H_    32
#define HKV_  8
#define G_    4      // H / HKV
#define D_    128
#define DV_   128
#define S_    8192
#define M_    64
#define BN_   64
#define KVSTRIDE (HKV_ * D_)     // 1024 floats between consecutive positions

#define CHUNK_ 16                // rows per pipeline chunk (quarter KV block)
#define NBPW_  8                 // KV blocks per WG
#define SPLIT_ (M_ / NBPW_)      // 8 partials per (b,hkv)
#define NCTOT_ (NBPW_ * BN_ / CHUNK_)   // 32 chunks per WG

// Async global->LDS, 16 B per lane: LDS dest is wave-uniform base + lane*16,
// global src is per-lane (swizzle goes on the SOURCE address).
__device__ __forceinline__ void gload_lds16(const float* gsrc, float* lds_dst) {
    __builtin_amdgcn_global_load_lds(
        (const __attribute__((address_space(1))) void*)gsrc,
        (__attribute__((address_space(3))) void*)lds_dst,
        16, 0, 0);
}

__device__ __forceinline__ float bcast_lane(float v, int srclane) {
    return __uint_as_float(__builtin_amdgcn_readlane(__float_as_uint(v), srclane));
}

// ---------------------------------------------------------------------------
// Kernel 1: 1024 persistent WGs at 4 WG/CU (LDS 32 KB/WG) — doubles the
// number of independent counted-vmcnt streams per CU vs R5, smoothing HBM
// issue. Each WG: one (b,hkv), 8 consecutive blocks (oct), ONE partial out
// (online softmax continues across all 8 blocks — no mid-stream stores).
//
// 256 threads = 4 waves; wave w = head g. XCD grouping: blockIdx%8 == hkv.
//
// Pipeline at 16-row chunk granularity, 2 global_load_lds (1 KB each) per
// wave per K/V stage. Steady state (traced): outstanding 6 -> wait vmcnt(4)
// drains oldest group; tail chunk uses (2, 0).
//   iter cc: wait vmcnt(4) -> barrier -> QK(K[cc]) ; issue V[cc+1]
//            wait vmcnt(4) -> barrier -> issue K[cc+2] ; softmax+PV(V[cc])
// ---------------------------------------------------------------------------
__global__ __launch_bounds__(256)
void sfa_partial(const float* __restrict__ q,
                 const float* __restrict__ K,
                 const float* __restrict__ V,
                 const int*   __restrict__ blk_idx,
                 const int*   __restrict__ seqlens,
                 float* __restrict__ o_ws,    // [B*HKV*G*SPLIT_][DV]
                 float* __restrict__ ml_ws)   // [B*HKV*G*SPLIT_][2]
{
    __shared__ float Klds[2][CHUNK_ * D_];   // 2 x 8 KB, swizzled granules
    __shared__ float Vlds[2][CHUNK_ * DV_];  // 2 x 8 KB, linear

    const int w    = blockIdx.x;        // 0..1023
    const int hkv  = w & 7;             // == XCD id (round-robin dispatch)
    const int t    = w >> 3;            // 0..127
    const int b    = t & 15;
    const int oct  = t >> 4;            // 0..7: which 8-block span
    const int bh   = b * HKV_ + hkv;

    const int tid  = threadIdx.x;
    const int wave = tid >> 6;          // == head-in-group g
    const int lane = tid & 63;
    const int c    = lane & 3;          // 16-B granule column within 64 B
    const int jr   = lane >> 2;         // key index (16 keys per chunk)

    const int h = hkv * G_ + wave;
    // 1/sqrt(128) * log2(e): scores land directly in exp2 domain
    const float kscale = 0.08838834764831845f * 1.4426950408889634f;

    // q4[f] = q[f*16 + c*4 .. +3], pre-scaled (granule index g = f*4 + c)
    float4 q4[8];
    {
        const float* qp = q + (size_t)(b * H_ + h) * D_ + c * 4;
        #pragma unroll
        for (int f = 0; f < 8; ++f) {
            float4 tq = *(const float4*)(qp + f * 16);
            q4[f] = make_float4(tq.x * kscale, tq.y * kscale,
                                tq.z * kscale, tq.w * kscale);
        }
    }

    // 8 block ids parked in lanes 0-7
    int vblk = 0;
    if (lane < NBPW_) vblk = blk_idx[bh * M_ + oct * NBPW_ + lane];

    const int seqlen = seqlens[b];
    const float* Kb = K + (size_t)b * S_ * KVSTRIDE + hkv * D_;
    const float* Vb = V + (size_t)b * S_ * KVSTRIDE + hkv * D_;

    // Drain prologue loads so the counted vmcnt waits start exact.
    asm volatile("s_waitcnt vmcnt(0)" ::: "memory");

    // Stage one 16-row chunk (8 KB): 2 instrs/wave, 1 KB each.
    // Instr p (0..7) covers rows {2p, 2p+1}; lane -> row 2p+(lane>>5),
    // granule slot lane&31. K source granule = slot ^ (row&7) so the later
    // strided ds_read_b128 QK reads are bank-conflict-free (verified: 0
    // SQ_LDS_BANK_CONFLICT with the identical layout in R4/R5).
    auto stageK = [&](int cc, int blk) {
        const int blkc = (blk < 0) ? 0 : blk;          // clamp: loads stay legal
        const size_t rowbase = (size_t)blkc * BN_ + (cc & 3) * CHUNK_;
        float* dst = &Klds[cc & 1][0];
        #pragma unroll
        for (int i = 0; i < 2; ++i) {
            const int p   = wave * 2 + i;              // 0..7
            const int row = 2 * p + (lane >> 5);       // 0..15
            const int g16 = lane & 31;
            const float* src = Kb + (rowbase + row) * KVSTRIDE
                                  + ((g16 ^ (row & 7)) << 2);
            gload_lds16(src, dst + p * 256);
        }
    };
    auto stageV = [&](int cc, int blk) {
        const int blkc = (blk < 0) ? 0 : blk;
        const size_t rowbase = (size_t)blkc * BN_ + (cc & 3) * CHUNK_;
        float* dst = &Vlds[cc & 1][0];
        #pragma unroll
        for (int i = 0; i < 2; ++i) {
            const int p   = wave * 2 + i;
            const int row = 2 * p + (lane >> 5);
            const int g16 = lane & 31;
            const float* src = Vb + (rowbase + row) * KVSTRIDE + (g16 << 2);
            gload_lds16(src, dst + p * 256);
        }
    };
    // block id of chunk cc (4 chunks per block), uniform
    auto blkOf = [&](int cc) -> int {
        return __builtin_amdgcn_readlane(vblk, cc >> 2);
    };

    float m  = -INFINITY;
    float l  = 0.f;
    float o0 = 0.f, o1 = 0.f;   // output dims 2*lane, 2*lane+1 (unnormalized)

    stageK(0, blkOf(0));
    stageV(0, blkOf(0));
    stageK(1, blkOf(1));

    #pragma unroll 2
    for (int cc = 0; cc < NCTOT_; ++cc) {
        const int  blk  = blkOf(cc);
        const bool bval = (blk >= 0);
        const int  pos0 = ((blk < 0) ? 0 : blk) * BN_ + (cc & 3) * CHUNK_;
        const bool last = (cc == NCTOT_ - 1);

        // ---- K[cc] ready ----
        if (last) asm volatile("s_waitcnt vmcnt(2)" ::: "memory");
        else      asm volatile("s_waitcnt vmcnt(4)" ::: "memory");
        __builtin_amdgcn_s_barrier();
        __builtin_amdgcn_sched_barrier(0);

        // ---- QK^T from LDS: 16 scores for this wave's head ----
        float s0;
        {
            const float* kr = &Klds[cc & 1][jr * D_];
            float acc = 0.f;
            #pragma unroll
            for (int f = 0; f < 8; ++f) {
                const int gg = (((f * 4 + c) ^ (jr & 7)) << 2);
                float4 k4 = *(const float4*)(kr + gg);
                acc += q4[f].x * k4.x;
                acc += q4[f].y * k4.y;
                acc += q4[f].z * k4.z;
                acc += q4[f].w * k4.w;
            }
            acc += __shfl_xor(acc, 1);
            acc += __shfl_xor(acc, 2);
            s0 = (bval && (pos0 + jr) < seqlen) ? acc : -INFINITY;
        }

        if (cc + 1 < NCTOT_) stageV(cc + 1, blkOf(cc + 1));

        // ---- V[cc] ready ----
        if (last) asm volatile("s_waitcnt vmcnt(0)" ::: "memory");
        else      asm volatile("s_waitcnt vmcnt(4)" ::: "memory");
        __builtin_amdgcn_s_barrier();
        __builtin_amdgcn_sched_barrier(0);

        if (cc + 2 < NCTOT_) stageK(cc + 2, blkOf(cc + 2));

        // ---- online softmax (exp2 domain) ----
        float bmax = s0;
        #pragma unroll
        for (int off = 4; off < 64; off <<= 1)
            bmax = fmaxf(bmax, __shfl_xor(bmax, off));

        const float newm = fmaxf(m, bmax);
        if (newm != -INFINITY) {        // wave-uniform; no barriers inside
            const float rr = __builtin_amdgcn_exp2f(m - newm);   // m=-inf -> 0
            const float p0 = __builtin_amdgcn_exp2f(s0 - newm);
            float ps = p0;
            #pragma unroll
            for (int off = 4; off < 64; off <<= 1)
                ps += __shfl_xor(ps, off);

            l  = l * rr + ps;
            o0 *= rr;
            o1 *= rr;
            m  = newm;

            // ---- PV from LDS: lane owns dims (2*lane, 2*lane+1) ----
            const float* vp0 = &Vlds[cc & 1][lane * 2];
            #pragma unroll
            for (int jj = 0; jj < 16; ++jj) {
                const float pj = bcast_lane(p0, jj * 4);
                const float2 v2 = *(const float2*)(vp0 + jj * DV_);
                o0 += pj * v2.x;
                o1 += pj * v2.y;
            }
        }
    }

    // ---- write the single partial for this WG ----
    const int pidx = (bh * G_ + wave) * SPLIT_ + oct;
    *(float2*)(o_ws + (size_t)pidx * DV_ + lane * 2) = make_float2(o0, o1);
    if (lane == 0)
        *(float2*)(ml_ws + pidx * 2) = make_float2(m, l);
}

// ---------------------------------------------------------------------------
// Kernel 2: combine SPLIT partials per (b, h). One wave per output row;
// lane sp holds (m,l) of partial sp, factors broadcast via readlane.
// ---------------------------------------------------------------------------
template<int SPLIT>
__global__ __launch_bounds__(64)
void sfa_reduce(const float* __restrict__ o_ws,
                const float* __restrict__ ml_ws,
                float* __restrict__ out)
{
    const int bhg  = blockIdx.x;            // == b*H + h
    const int lane = threadIdx.x;

    float mi = -INFINITY, li = 0.f;
    if (lane < SPLIT) {
        const float2 t = ((const float2*)ml_ws)[bhg * SPLIT + lane];
        mi = t.x; li = t.y;
    }
    float mfull = mi;
    #pragma unroll
    for (int off = 1; off < 64; off <<= 1)
        mfull = fmaxf(mfull, __shfl_xor(mfull, off));

    const float f = (mi == -INFINITY) ? 0.f
                  : __builtin_amdgcn_exp2f(mi - mfull);
    float L = li * f;
    #pragma unroll
    for (int off = 1; off < 64; off <<= 1)
        L += __shfl_xor(L, off);

    float o0 = 0.f, o1 = 0.f;
    #pragma unroll
    for (int i = 0; i < SPLIT; ++i) {
        const float fi = bcast_lane(f, i);  // uniform
        if (fi != 0.f) {
            const float* op = o_ws + (size_t)(bhg * SPLIT + i) * DV_ + lane * 2;
            o0 += fi * op[0];
            o1 += fi * op[1];
        }
    }
    const float inv = (L > 0.f) ? (1.f / L) : 0.f;
    out[(size_t)bhg * DV_ + lane * 2]     = o0 * inv;
    out[(size_t)bhg * DV_ + lane * 2 + 1] = o1 * inv;
}

// ---------------------------------------------------------------------------
extern "C" void kernel_launch(void* const* d_in, const int* in_sizes, int n_in,
                              void* d_out, int out_size, void* d_ws, size_t ws_size,
                              hipStream_t stream) {
    const float* q    = (const float*)d_in[0];
    const float* K    = (const float*)d_in[1];
    const float* V    = (const float*)d_in[2];
    const int*   bidx = (const int*)d_in[3];
    const int*   slen = (const int*)d_in[4];
    // d_in[5] = block_size (==BN_), compile-time constant here

    // ws need: 16*8*4*8*128 floats (2.1 MB) + 32 KB of (m,l)
    float* o_ws  = (float*)d_ws;
    float* ml_ws = o_ws + (size_t)B_ * HKV_ * G_ * SPLIT_ * DV_;

    sfa_partial<<<B_ * HKV_ * SPLIT_, 256, 0, stream>>>(
        q, K, V, bidx, slen, o_ws, ml_ws);

    sfa_reduce<SPLIT_><<<B_ * H_, 64, 0, stream>>>(o_ws, ml_ws, (float*)d_out);
}